// Round 1
// baseline (2539.439 us; speedup 1.0000x reference)
//
#include <hip/hip_runtime.h>
#include <hip/hip_fp16.h>

#define B_ 32
#define T_ 336
#define NH 100
#define NM 150
#define FH 8
#define FM 16
#define HG 64
#define FUT 24
#define EH 300
#define EM 500

// ws layout in 4-byte elements
#define WRELH 0       // 8*64 combined 0.5*W_rel_h, transposed [k][j]
#define WRELM 512     // 16*64
#define WROOT 1536    // 8*64  combined 0.5*(W_root_h+W_root_m), transposed
#define BIASC 2048    // 64
#define OFFH  2112    // 101 ints
#define SRCH  2304    // 300 ints
#define OFFM  2624    // 101 ints
#define SRCM  2752    // 500 ints
#define XBUF_F 4096   // fp16 x buffer [G][NH][HG] starts here (float-element offset)

#define WPAD 68       // padded LDS row stride (floats) for weight/x/h rows

__device__ __forceinline__ float fsigmoid(float x) {
    return __builtin_amdgcn_rcpf(1.0f + __expf(-x));
}
__device__ __forceinline__ float ftanh(float x) {
    // tanh(x) = 1 - 2/(exp(2x)+1); inf/0 limits degrade gracefully to +/-1
    return 1.0f - 2.0f * __builtin_amdgcn_rcpf(1.0f + __expf(2.0f * x));
}
__device__ __forceinline__ float lrelu(float x) { return x >= 0.0f ? x : 0.01f * x; }

// ---------------------------------------------------------------- prep ------
__global__ __launch_bounds__(256) void prep_kernel(
    const float* __restrict__ W_rel_m, const float* __restrict__ b_rel_m,
    const float* __restrict__ W_root_m, const float* __restrict__ W_rel_h,
    const float* __restrict__ b_rel_h, const float* __restrict__ W_root_h,
    const int* __restrict__ he, const int* __restrict__ me,
    float* __restrict__ ws)
{
    const int tid = threadIdx.x;
    int* wsI = (int*)ws;
    __shared__ int cnt[NH + 1];
    __shared__ int cur[NH + 1];

    // combined + transposed small weights (fold the 0.5 hetero-mean in)
    for (int idx = tid; idx < HG * FH; idx += 256) {
        int j = idx >> 3, k = idx & 7;
        ws[WRELH + k * HG + j] = 0.5f * W_rel_h[j * FH + k];
        ws[WROOT + k * HG + j] = 0.5f * (W_root_h[j * FH + k] + W_root_m[j * FH + k]);
    }
    for (int idx = tid; idx < HG * FM; idx += 256) {
        int j = idx >> 4, k = idx & 15;
        ws[WRELM + k * HG + j] = 0.5f * W_rel_m[j * FM + k];
    }
    if (tid < HG) ws[BIASC + tid] = 0.5f * (b_rel_h[tid] + b_rel_m[tid]);

    // ---- hydro CSR (tgt -> list of src) ----
    if (tid <= NH) cnt[tid] = 0;
    __syncthreads();
    for (int e = tid; e < EH; e += 256) atomicAdd(&cnt[he[EH + e]], 1);
    __syncthreads();
    if (tid == 0) {
        int s = 0;
        for (int n2 = 0; n2 < NH; ++n2) { int c = cnt[n2]; cur[n2] = s; cnt[n2] = s; s += c; }
        cnt[NH] = s;
    }
    __syncthreads();
    if (tid <= NH) wsI[OFFH + tid] = cnt[tid];
    for (int e = tid; e < EH; e += 256) {
        int t = he[EH + e];
        int p = atomicAdd(&cur[t], 1);
        wsI[SRCH + p] = he[e];
    }
    __syncthreads();

    // ---- meteo CSR ----
    if (tid <= NH) cnt[tid] = 0;
    __syncthreads();
    for (int e = tid; e < EM; e += 256) atomicAdd(&cnt[me[EM + e]], 1);
    __syncthreads();
    if (tid == 0) {
        int s = 0;
        for (int n2 = 0; n2 < NH; ++n2) { int c = cnt[n2]; cur[n2] = s; cnt[n2] = s; s += c; }
        cnt[NH] = s;
    }
    __syncthreads();
    if (tid <= NH) wsI[OFFM + tid] = cnt[tid];
    for (int e = tid; e < EM; e += 256) {
        int t = me[EM + e];
        int p = atomicAdd(&cur[t], 1);
        wsI[SRCM + p] = me[e];
    }
}

// ---------------------------------------------------------------- GNN -------
// one block per graph g in [0, B*T); writes x[g][n][j] as fp16
__global__ __launch_bounds__(256) void gnn_kernel(
    const float* __restrict__ dm, const float* __restrict__ dh,
    const float* __restrict__ ws, __half* __restrict__ xout)
{
    __shared__ __align__(16) float xh[NH * FH];       // 800
    __shared__ __align__(16) float xm[NM * FM];       // 2400
    __shared__ __align__(16) float aggh[NH * FH];     // 800
    __shared__ __align__(16) float aggm[NH * FM];     // 1600
    __shared__ __align__(16) float wrelh[FH * HG];    // 512
    __shared__ __align__(16) float wrelm[FM * HG];    // 1024
    __shared__ __align__(16) float wroot[FH * HG];    // 512
    __shared__ __align__(16) float biasc[HG];
    __shared__ int offh[NH + 1], offm[NH + 1];
    __shared__ int srch[EH], srcm[EM];

    const int tid = threadIdx.x;
    const int g = blockIdx.x;
    const int* wsI = (const int*)ws;

    {
        const float4* s = (const float4*)(dh + (size_t)g * (NH * FH));
        for (int i = tid; i < (NH * FH) / 4; i += 256) ((float4*)xh)[i] = s[i];
    }
    {
        const float4* s = (const float4*)(dm + (size_t)g * (NM * FM));
        for (int i = tid; i < (NM * FM) / 4; i += 256) ((float4*)xm)[i] = s[i];
    }
    for (int i = tid; i < (FH * HG) / 4; i += 256) {
        ((float4*)wrelh)[i] = ((const float4*)(ws + WRELH))[i];
        ((float4*)wroot)[i] = ((const float4*)(ws + WROOT))[i];
    }
    for (int i = tid; i < (FM * HG) / 4; i += 256)
        ((float4*)wrelm)[i] = ((const float4*)(ws + WRELM))[i];
    if (tid < HG) biasc[tid] = ws[BIASC + tid];
    for (int i = tid; i <= NH; i += 256) { offh[i] = wsI[OFFH + i]; offm[i] = wsI[OFFM + i]; }
    for (int i = tid; i < EH; i += 256) srch[i] = wsI[SRCH + i];
    for (int i = tid; i < EM; i += 256) srcm[i] = wsI[SRCM + i];
    __syncthreads();

    // sum-aggregate neighbors (CSR gather, no atomics)
    for (int s = tid; s < NH * FH; s += 256) {
        int n = s >> 3, k = s & 7;
        float a = 0.f;
        for (int e = offh[n]; e < offh[n + 1]; ++e) a += xh[srch[e] * FH + k];
        aggh[s] = a;
    }
    for (int s = tid; s < NH * FM; s += 256) {
        int n = s >> 4, k = s & 15;
        float a = 0.f;
        for (int e = offm[n]; e < offm[n + 1]; ++e) a += xm[srcm[e] * FM + k];
        aggm[s] = a;
    }
    __syncthreads();

    __half* xg = xout + (size_t)g * (NH * HG);
    for (int task = tid; task < NH * 16; task += 256) {
        int n = task >> 4;
        int j0 = (task & 15) << 2;
        float4 acc = *(const float4*)&biasc[j0];
#pragma unroll
        for (int k = 0; k < FH; ++k) {
            float a = aggh[n * FH + k];
            float4 w = *(const float4*)&wrelh[k * HG + j0];
            acc.x += a * w.x; acc.y += a * w.y; acc.z += a * w.z; acc.w += a * w.w;
        }
#pragma unroll
        for (int k = 0; k < FM; ++k) {
            float a = aggm[n * FM + k];
            float4 w = *(const float4*)&wrelm[k * HG + j0];
            acc.x += a * w.x; acc.y += a * w.y; acc.z += a * w.z; acc.w += a * w.w;
        }
#pragma unroll
        for (int k = 0; k < FH; ++k) {
            float a = xh[n * FH + k];
            float4 w = *(const float4*)&wroot[k * HG + j0];
            acc.x += a * w.x; acc.y += a * w.y; acc.z += a * w.z; acc.w += a * w.w;
        }
        acc.x = lrelu(acc.x); acc.y = lrelu(acc.y); acc.z = lrelu(acc.z); acc.w = lrelu(acc.w);
        __half2 lo = __halves2half2(__float2half_rn(acc.x), __float2half_rn(acc.y));
        __half2 hi = __halves2half2(__float2half_rn(acc.z), __float2half_rn(acc.w));
        *(__half2*)(xg + n * HG + j0) = lo;
        *(__half2*)(xg + n * HG + j0 + 2) = hi;
    }
}

// ---------------------------------------------------------------- LSTM ------
// block = (node n, batch-half); 1024 threads = 16 waves; weights in LDS.
// thread -> (b = lane>>2 in [0,16), u = 4*wave + (lane&3) in [0,64)):
// owns all 4 gates of hidden unit u for batch b; c lives in a register.
__global__ __launch_bounds__(1024) void lstm_kernel(
    const __half* __restrict__ xbuf,
    const float* __restrict__ Wih, const float* __restrict__ Whh,
    const float* __restrict__ bih, const float* __restrict__ bhh,
    const float* __restrict__ Wlin, const float* __restrict__ blin,
    float* __restrict__ out)
{
    __shared__ __align__(16) float wi[256 * WPAD];   // 69632 B
    __shared__ __align__(16) float wh[256 * WPAD];   // 69632 B
    __shared__ __align__(16) float hbuf[16 * WPAD];  // 4352 B
    __shared__ __align__(16) float xs[16 * WPAD];    // 4352 B

    const int tid = threadIdx.x;
    const int n = blockIdx.x >> 1;
    const int half = blockIdx.x & 1;

    // stage weights: global coalesced float4 -> padded LDS rows
    {
        const float4* gi = (const float4*)(Wih + (size_t)n * 256 * 64);
        const float4* gh = (const float4*)(Whh + (size_t)n * 256 * 64);
#pragma unroll
        for (int c = 0; c < 4; ++c) {
            int i4 = tid + c * 1024;
            int flat = i4 << 2;
            int r = flat >> 6, k = flat & 63;
            *(float4*)&wi[r * WPAD + k] = gi[i4];
            *(float4*)&wh[r * WPAD + k] = gh[i4];
        }
    }
    for (int i = tid; i < 16 * WPAD; i += 1024) hbuf[i] = 0.f;

    const int wave = tid >> 6, lane = tid & 63;
    const int u = (wave << 2) | (lane & 3);
    const int b = lane >> 2;

    const float bias_i = bih[n * 256 + u]       + bhh[n * 256 + u];
    const float bias_f = bih[n * 256 + 64 + u]  + bhh[n * 256 + 64 + u];
    const float bias_g = bih[n * 256 + 128 + u] + bhh[n * 256 + 128 + u];
    const float bias_o = bih[n * 256 + 192 + u] + bhh[n * 256 + 192 + u];

    // x staging: thread (xb = wave, xk = lane) loads one fp16 element per step
    const int xb = tid >> 6;
    const int xk = tid & 63;
    const int gb = half * 16 + xb;                      // global batch
    const __half* xp = xbuf + (size_t)gb * T_ * (NH * HG) + (size_t)n * HG + xk;
    const size_t xstep = (size_t)NH * HG;

    {   // t = 0
        __half h0 = *xp;
        xs[xb * WPAD + xk] = __half2float(h0);
    }
    __syncthreads();

    const float* wi0 = &wi[(u      ) * WPAD];
    const float* wi1 = &wi[(u + 64 ) * WPAD];
    const float* wi2 = &wi[(u + 128) * WPAD];
    const float* wi3 = &wi[(u + 192) * WPAD];
    const float* wh0 = &wh[(u      ) * WPAD];
    const float* wh1 = &wh[(u + 64 ) * WPAD];
    const float* wh2 = &wh[(u + 128) * WPAD];
    const float* wh3 = &wh[(u + 192) * WPAD];
    const float* xrow = &xs[b * WPAD];
    const float* hrow = &hbuf[b * WPAD];

    float cc = 0.f;
#pragma unroll 1
    for (int t = 0; t < T_; ++t) {
        // prefetch x[t+1]; conversion deferred until after the dot phase
        __half xn_h = __float2half_rn(0.0f);
        if (t + 1 < T_) xn_h = xp[(size_t)(t + 1) * xstep];

        float ai = bias_i, af = bias_f, ag = bias_g, ao = bias_o;
#pragma unroll 4
        for (int k4 = 0; k4 < 16; ++k4) {
            const int o = k4 << 2;
            float4 xv = *(const float4*)&xrow[o];
            float4 hv = *(const float4*)&hrow[o];
            float4 a0 = *(const float4*)&wi0[o];
            float4 a1 = *(const float4*)&wi1[o];
            float4 a2 = *(const float4*)&wi2[o];
            float4 a3 = *(const float4*)&wi3[o];
            float4 c0 = *(const float4*)&wh0[o];
            float4 c1 = *(const float4*)&wh1[o];
            float4 c2 = *(const float4*)&wh2[o];
            float4 c3 = *(const float4*)&wh3[o];
            ai += a0.x * xv.x + a0.y * xv.y + a0.z * xv.z + a0.w * xv.w
                + c0.x * hv.x + c0.y * hv.y + c0.z * hv.z + c0.w * hv.w;
            af += a1.x * xv.x + a1.y * xv.y + a1.z * xv.z + a1.w * xv.w
                + c1.x * hv.x + c1.y * hv.y + c1.z * hv.z + c1.w * hv.w;
            ag += a2.x * xv.x + a2.y * xv.y + a2.z * xv.z + a2.w * xv.w
                + c2.x * hv.x + c2.y * hv.y + c2.z * hv.z + c2.w * hv.w;
            ao += a3.x * xv.x + a3.y * xv.y + a3.z * xv.z + a3.w * xv.w
                + c3.x * hv.x + c3.y * hv.y + c3.z * hv.z + c3.w * hv.w;
        }
        float ig = fsigmoid(ai);
        float fg = fsigmoid(af);
        float gg = ftanh(ag);
        float og = fsigmoid(ao);
        cc = fg * cc + ig * gg;
        float hn = og * ftanh(cc);

        __syncthreads();                 // all reads of h_{t-1}/x_t done
        hbuf[b * WPAD + u] = hn;
        xs[xb * WPAD + xk] = __half2float(xn_h);
        __syncthreads();                 // h_t and x_{t+1} visible
    }

    // fused head: pred = leaky(h_T @ W_lin^T + b_lin)
    if (tid < 16 * FUT) {
        int bb = tid / FUT, j = tid - bb * FUT;
        float acc = blin[j];
        const float* wl = Wlin + j * 64;
        const float* hr2 = &hbuf[bb * WPAD];
#pragma unroll
        for (int k = 0; k < 64; k += 4) {
            float4 w = *(const float4*)&wl[k];
            acc += w.x * hr2[k] + w.y * hr2[k + 1] + w.z * hr2[k + 2] + w.w * hr2[k + 3];
        }
        out[((size_t)(half * 16 + bb) * NH + n) * FUT + j] = lrelu(acc);
    }
}

// ---------------------------------------------------------------- launch ----
extern "C" void kernel_launch(void* const* d_in, const int* in_sizes, int n_in,
                              void* d_out, int out_size, void* d_ws, size_t ws_size,
                              hipStream_t stream)
{
    const float* dm       = (const float*)d_in[0];
    const float* dh       = (const float*)d_in[1];
    const int*   he       = (const int*)d_in[2];
    const int*   me       = (const int*)d_in[3];
    const float* W_rel_m  = (const float*)d_in[4];
    const float* b_rel_m  = (const float*)d_in[5];
    const float* W_root_m = (const float*)d_in[6];
    const float* W_rel_h  = (const float*)d_in[7];
    const float* b_rel_h  = (const float*)d_in[8];
    const float* W_root_h = (const float*)d_in[9];
    const float* Wih      = (const float*)d_in[10];
    const float* Whh      = (const float*)d_in[11];
    const float* bih      = (const float*)d_in[12];
    const float* bhh      = (const float*)d_in[13];
    const float* Wlin     = (const float*)d_in[14];
    const float* blin     = (const float*)d_in[15];

    float* ws = (float*)d_ws;
    __half* xbuf = (__half*)(ws + XBUF_F);
    float* out = (float*)d_out;

    prep_kernel<<<1, 256, 0, stream>>>(W_rel_m, b_rel_m, W_root_m,
                                       W_rel_h, b_rel_h, W_root_h, he, me, ws);
    gnn_kernel<<<B_ * T_, 256, 0, stream>>>(dm, dh, ws, xbuf);
    lstm_kernel<<<NH * 2, 1024, 0, stream>>>(xbuf, Wih, Whh, bih, bhh, Wlin, blin, out);
}

// Round 2
// 583.238 us; speedup vs baseline: 4.3540x; 4.3540x over previous
//
#include <hip/hip_runtime.h>
#include <hip/hip_fp16.h>

#define B_ 32
#define T_ 336
#define NH 100
#define NM 150
#define FH 8
#define FM 16
#define HG 64
#define FUT 24
#define EH 300
#define EM 500

// ws layout in 4-byte elements
#define WRELH 0       // 8*64 combined 0.5*W_rel_h, transposed [k][j]
#define WRELM 512     // 16*64
#define WROOT 1536    // 8*64  combined 0.5*(W_root_h+W_root_m), transposed
#define BIASC 2048    // 64
#define OFFH  2112    // 101 ints
#define SRCH  2304    // 300 ints
#define OFFM  2624    // 101 ints
#define SRCM  2752    // 500 ints
#define XBUF_F 4096   // fp16 x buffer [G][NH][HG] starts here (float-element offset)

typedef _Float16 half8 __attribute__((ext_vector_type(8)));
typedef float floatx4 __attribute__((ext_vector_type(4)));

#define XH_STRIDE 136   // fp16 elems per row of [x|h] LDS tile (272B, 16B-aligned, bank-uniform)
#define GSTRIDE   266   // fp32 words per gates row: 4*266 % 32 == 8 -> conflict-free C writes

__device__ __forceinline__ float fsigmoid(float x) {
    return __builtin_amdgcn_rcpf(1.0f + __expf(-x));
}
__device__ __forceinline__ float ftanh(float x) {
    return 1.0f - 2.0f * __builtin_amdgcn_rcpf(1.0f + __expf(2.0f * x));
}
__device__ __forceinline__ float lrelu(float x) { return x >= 0.0f ? x : 0.01f * x; }

// ---------------------------------------------------------------- prep ------
__global__ __launch_bounds__(256) void prep_kernel(
    const float* __restrict__ W_rel_m, const float* __restrict__ b_rel_m,
    const float* __restrict__ W_root_m, const float* __restrict__ W_rel_h,
    const float* __restrict__ b_rel_h, const float* __restrict__ W_root_h,
    const int* __restrict__ he, const int* __restrict__ me,
    float* __restrict__ ws)
{
    const int tid = threadIdx.x;
    int* wsI = (int*)ws;
    __shared__ int cnt[NH + 1];
    __shared__ int cur[NH + 1];

    for (int idx = tid; idx < HG * FH; idx += 256) {
        int j = idx >> 3, k = idx & 7;
        ws[WRELH + k * HG + j] = 0.5f * W_rel_h[j * FH + k];
        ws[WROOT + k * HG + j] = 0.5f * (W_root_h[j * FH + k] + W_root_m[j * FH + k]);
    }
    for (int idx = tid; idx < HG * FM; idx += 256) {
        int j = idx >> 4, k = idx & 15;
        ws[WRELM + k * HG + j] = 0.5f * W_rel_m[j * FM + k];
    }
    if (tid < HG) ws[BIASC + tid] = 0.5f * (b_rel_h[tid] + b_rel_m[tid]);

    // ---- hydro CSR (tgt -> list of src) ----
    if (tid <= NH) cnt[tid] = 0;
    __syncthreads();
    for (int e = tid; e < EH; e += 256) atomicAdd(&cnt[he[EH + e]], 1);
    __syncthreads();
    if (tid == 0) {
        int s = 0;
        for (int n2 = 0; n2 < NH; ++n2) { int c = cnt[n2]; cur[n2] = s; cnt[n2] = s; s += c; }
        cnt[NH] = s;
    }
    __syncthreads();
    if (tid <= NH) wsI[OFFH + tid] = cnt[tid];
    for (int e = tid; e < EH; e += 256) {
        int t = he[EH + e];
        int p = atomicAdd(&cur[t], 1);
        wsI[SRCH + p] = he[e];
    }
    __syncthreads();

    // ---- meteo CSR ----
    if (tid <= NH) cnt[tid] = 0;
    __syncthreads();
    for (int e = tid; e < EM; e += 256) atomicAdd(&cnt[me[EM + e]], 1);
    __syncthreads();
    if (tid == 0) {
        int s = 0;
        for (int n2 = 0; n2 < NH; ++n2) { int c = cnt[n2]; cur[n2] = s; cnt[n2] = s; s += c; }
        cnt[NH] = s;
    }
    __syncthreads();
    if (tid <= NH) wsI[OFFM + tid] = cnt[tid];
    for (int e = tid; e < EM; e += 256) {
        int t = me[EM + e];
        int p = atomicAdd(&cur[t], 1);
        wsI[SRCM + p] = me[e];
    }
}

// ---------------------------------------------------------------- GNN -------
__global__ __launch_bounds__(256) void gnn_kernel(
    const float* __restrict__ dm, const float* __restrict__ dh,
    const float* __restrict__ ws, __half* __restrict__ xout)
{
    __shared__ __align__(16) float xh[NH * FH];
    __shared__ __align__(16) float xm[NM * FM];
    __shared__ __align__(16) float aggh[NH * FH];
    __shared__ __align__(16) float aggm[NH * FM];
    __shared__ __align__(16) float wrelh[FH * HG];
    __shared__ __align__(16) float wrelm[FM * HG];
    __shared__ __align__(16) float wroot[FH * HG];
    __shared__ __align__(16) float biasc[HG];
    __shared__ int offh[NH + 1], offm[NH + 1];
    __shared__ int srch[EH], srcm[EM];

    const int tid = threadIdx.x;
    const int g = blockIdx.x;
    const int* wsI = (const int*)ws;

    {
        const float4* s = (const float4*)(dh + (size_t)g * (NH * FH));
        for (int i = tid; i < (NH * FH) / 4; i += 256) ((float4*)xh)[i] = s[i];
    }
    {
        const float4* s = (const float4*)(dm + (size_t)g * (NM * FM));
        for (int i = tid; i < (NM * FM) / 4; i += 256) ((float4*)xm)[i] = s[i];
    }
    for (int i = tid; i < (FH * HG) / 4; i += 256) {
        ((float4*)wrelh)[i] = ((const float4*)(ws + WRELH))[i];
        ((float4*)wroot)[i] = ((const float4*)(ws + WROOT))[i];
    }
    for (int i = tid; i < (FM * HG) / 4; i += 256)
        ((float4*)wrelm)[i] = ((const float4*)(ws + WRELM))[i];
    if (tid < HG) biasc[tid] = ws[BIASC + tid];
    for (int i = tid; i <= NH; i += 256) { offh[i] = wsI[OFFH + i]; offm[i] = wsI[OFFM + i]; }
    for (int i = tid; i < EH; i += 256) srch[i] = wsI[SRCH + i];
    for (int i = tid; i < EM; i += 256) srcm[i] = wsI[SRCM + i];
    __syncthreads();

    for (int s = tid; s < NH * FH; s += 256) {
        int n = s >> 3, k = s & 7;
        float a = 0.f;
        for (int e = offh[n]; e < offh[n + 1]; ++e) a += xh[srch[e] * FH + k];
        aggh[s] = a;
    }
    for (int s = tid; s < NH * FM; s += 256) {
        int n = s >> 4, k = s & 15;
        float a = 0.f;
        for (int e = offm[n]; e < offm[n + 1]; ++e) a += xm[srcm[e] * FM + k];
        aggm[s] = a;
    }
    __syncthreads();

    __half* xg = xout + (size_t)g * (NH * HG);
    for (int task = tid; task < NH * 16; task += 256) {
        int n = task >> 4;
        int j0 = (task & 15) << 2;
        float4 acc = *(const float4*)&biasc[j0];
#pragma unroll
        for (int k = 0; k < FH; ++k) {
            float a = aggh[n * FH + k];
            float4 w = *(const float4*)&wrelh[k * HG + j0];
            acc.x += a * w.x; acc.y += a * w.y; acc.z += a * w.z; acc.w += a * w.w;
        }
#pragma unroll
        for (int k = 0; k < FM; ++k) {
            float a = aggm[n * FM + k];
            float4 w = *(const float4*)&wrelm[k * HG + j0];
            acc.x += a * w.x; acc.y += a * w.y; acc.z += a * w.z; acc.w += a * w.w;
        }
#pragma unroll
        for (int k = 0; k < FH; ++k) {
            float a = xh[n * FH + k];
            float4 w = *(const float4*)&wroot[k * HG + j0];
            acc.x += a * w.x; acc.y += a * w.y; acc.z += a * w.z; acc.w += a * w.w;
        }
        acc.x = lrelu(acc.x); acc.y = lrelu(acc.y); acc.z = lrelu(acc.z); acc.w = lrelu(acc.w);
        __half2 lo = __halves2half2(__float2half_rn(acc.x), __float2half_rn(acc.y));
        __half2 hi = __halves2half2(__float2half_rn(acc.z), __float2half_rn(acc.w));
        *(__half2*)(xg + n * HG + j0) = lo;
        *(__half2*)(xg + n * HG + j0 + 2) = hi;
    }
}

// ---------------------------------------------------------------- LSTM ------
// block = (node n, batch-half): 200 blocks x 512 threads (8 waves).
// Weights live in REGISTERS as MFMA B-fragments (no per-step weight LDS reads).
// Per step: gates[16b][256] = [x|h][16x128] @ W^T via v_mfma_f32_16x16x32_f16,
// bias folded into C-init; combine phase owns c in registers.
__global__ __launch_bounds__(512) void lstm_kernel(
    const __half* __restrict__ xbuf,
    const float* __restrict__ Wih, const float* __restrict__ Whh,
    const float* __restrict__ bih, const float* __restrict__ bhh,
    const float* __restrict__ Wlin, const float* __restrict__ blin,
    float* __restrict__ out)
{
    __shared__ __align__(16) _Float16 xh[16 * XH_STRIDE];   // [b][x(0..63)|h(64..127)]
    __shared__ __align__(16) float gates[16 * GSTRIDE];     // [b][256 gate cols]
    __shared__ __align__(16) float hb32[16 * 68];           // fp32 h_T for the head

    const int tid = threadIdx.x;
    const int n = blockIdx.x >> 1;
    const int half_ = blockIdx.x & 1;
    const int w = tid >> 6, l = tid & 63;
    const int m16 = l & 15, g4 = l >> 4;

    // ---- preload B-fragments (weights -> fp16 regs) + bias; one-time ----
    // B-frag lane layout for 16x16x32_f16: n-col = l&15, k = kt*32 + (l>>4)*8 + j
    half8 bf[2][4];
    float biasr[2];
#pragma unroll
    for (int gti = 0; gti < 2; ++gti) {
        const int gcol = 32 * w + 16 * gti + m16;           // 0..255
        const float* wi = Wih + ((size_t)n * 256 + gcol) * 64;
        const float* wh = Whh + ((size_t)n * 256 + gcol) * 64;
        biasr[gti] = bih[n * 256 + gcol] + bhh[n * 256 + gcol];
#pragma unroll
        for (int kt = 0; kt < 4; ++kt) {
            const int kb = kt * 32 + g4 * 8;                // 0..127
            const float* src = (kb < 64) ? (wi + kb) : (wh + (kb - 64));
            float4 lo = *(const float4*)src;
            float4 hi = *(const float4*)(src + 4);
            half8 f;
            f[0] = (_Float16)lo.x; f[1] = (_Float16)lo.y;
            f[2] = (_Float16)lo.z; f[3] = (_Float16)lo.w;
            f[4] = (_Float16)hi.x; f[5] = (_Float16)hi.y;
            f[6] = (_Float16)hi.z; f[7] = (_Float16)hi.w;
            bf[gti][kt] = f;
        }
    }
    const float bias0 = biasr[0], bias1 = biasr[1];

    // x staging ids (tid<256): pb = batch, pk = 4-fp16 chunk
    const unsigned short* xb_u = (const unsigned short*)xbuf;
    const int pb = tid >> 4;
    const int pk = (tid & 15) << 2;
    const size_t xrowbase = (size_t)(half_ * 16 + pb) * T_ * (NH * HG) + (size_t)n * HG + pk;

    // combine ids: each thread owns unit cu for two batches cb0, cb1
    const int cu = tid & 63;
    const int cb0 = (tid >> 6) * 2, cb1 = cb0 + 1;

    // ---- prologue: x[0] into LDS, h = 0 ----
    if (tid < 256) {
        ushort4 x0 = *(const ushort4*)(xb_u + xrowbase);
        *(ushort4*)((unsigned short*)xh + pb * XH_STRIDE + pk) = x0;
    }
    for (int i = tid; i < 16 * 64; i += 512)
        xh[(i >> 6) * XH_STRIDE + 64 + (i & 63)] = (_Float16)0.f;
    __syncthreads();

    float cc0 = 0.f, cc1 = 0.f;
    ushort4 xpre;

#pragma unroll 1
    for (int t = 0; t < T_; ++t) {
        // ---- P1: issue x[t+1] prefetch; A-frags; MFMA; write gates ----
        if (tid < 256) {
            const int tn = (t + 1 < T_) ? (t + 1) : (T_ - 1);
            xpre = *(const ushort4*)(xb_u + xrowbase + (size_t)tn * (NH * HG));
        }
        half8 af[4];
#pragma unroll
        for (int kt = 0; kt < 4; ++kt)
            af[kt] = *(const half8*)&xh[m16 * XH_STRIDE + kt * 32 + g4 * 8];

        floatx4 c0 = {bias0, bias0, bias0, bias0};
        floatx4 c1 = {bias1, bias1, bias1, bias1};
#pragma unroll
        for (int kt = 0; kt < 4; ++kt) {
            c0 = __builtin_amdgcn_mfma_f32_16x16x32_f16(af[kt], bf[0][kt], c0, 0, 0, 0);
            c1 = __builtin_amdgcn_mfma_f32_16x16x32_f16(af[kt], bf[1][kt], c1, 0, 0, 0);
        }
        // D layout: col = l&15, row(batch) = (l>>4)*4 + reg
#pragma unroll
        for (int r = 0; r < 4; ++r) {
            gates[(4 * g4 + r) * GSTRIDE + 32 * w + m16]      = c0[r];
            gates[(4 * g4 + r) * GSTRIDE + 32 * w + 16 + m16] = c1[r];
        }
        __syncthreads();

        // ---- P2: gate combine (c in regs), write h_t (fp16) and x[t+1] ----
        {
            float gi = gates[cb0 * GSTRIDE + cu];
            float gf = gates[cb0 * GSTRIDE + 64 + cu];
            float gg = gates[cb0 * GSTRIDE + 128 + cu];
            float go = gates[cb0 * GSTRIDE + 192 + cu];
            cc0 = fsigmoid(gf) * cc0 + fsigmoid(gi) * ftanh(gg);
            float h0 = fsigmoid(go) * ftanh(cc0);

            float gi1 = gates[cb1 * GSTRIDE + cu];
            float gf1 = gates[cb1 * GSTRIDE + 64 + cu];
            float gg1 = gates[cb1 * GSTRIDE + 128 + cu];
            float go1 = gates[cb1 * GSTRIDE + 192 + cu];
            cc1 = fsigmoid(gf1) * cc1 + fsigmoid(gi1) * ftanh(gg1);
            float h1 = fsigmoid(go1) * ftanh(cc1);

            xh[cb0 * XH_STRIDE + 64 + cu] = (_Float16)h0;
            xh[cb1 * XH_STRIDE + 64 + cu] = (_Float16)h1;
            if (t == T_ - 1) { hb32[cb0 * 68 + cu] = h0; hb32[cb1 * 68 + cu] = h1; }
        }
        if (tid < 256)
            *(ushort4*)((unsigned short*)xh + pb * XH_STRIDE + pk) = xpre;
        __syncthreads();
    }

    // ---- head: pred = leaky(h_T @ W_lin^T + b_lin), fp32 h ----
    if (tid < 16 * FUT) {
        int b = tid / FUT, j = tid - b * FUT;
        float acc = blin[j];
        const float* wl = Wlin + j * 64;
        const float* hr = &hb32[b * 68];
#pragma unroll
        for (int k = 0; k < 64; k += 4) {
            float4 wv = *(const float4*)&wl[k];
            acc += wv.x * hr[k] + wv.y * hr[k + 1] + wv.z * hr[k + 2] + wv.w * hr[k + 3];
        }
        out[((size_t)(half_ * 16 + b) * NH + n) * FUT + j] = lrelu(acc);
    }
}

// ---------------------------------------------------------------- launch ----
extern "C" void kernel_launch(void* const* d_in, const int* in_sizes, int n_in,
                              void* d_out, int out_size, void* d_ws, size_t ws_size,
                              hipStream_t stream)
{
    const float* dm       = (const float*)d_in[0];
    const float* dh       = (const float*)d_in[1];
    const int*   he       = (const int*)d_in[2];
    const int*   me       = (const int*)d_in[3];
    const float* W_rel_m  = (const float*)d_in[4];
    const float* b_rel_m  = (const float*)d_in[5];
    const float* W_root_m = (const float*)d_in[6];
    const float* W_rel_h  = (const float*)d_in[7];
    const float* b_rel_h  = (const float*)d_in[8];
    const float* W_root_h = (const float*)d_in[9];
    const float* Wih      = (const float*)d_in[10];
    const float* Whh      = (const float*)d_in[11];
    const float* bih      = (const float*)d_in[12];
    const float* bhh      = (const float*)d_in[13];
    const float* Wlin     = (const float*)d_in[14];
    const float* blin     = (const float*)d_in[15];

    float* ws = (float*)d_ws;
    __half* xbuf = (__half*)(ws + XBUF_F);
    float* out = (float*)d_out;

    prep_kernel<<<1, 256, 0, stream>>>(W_rel_m, b_rel_m, W_root_m,
                                       W_rel_h, b_rel_h, W_root_h, he, me, ws);
    gnn_kernel<<<B_ * T_, 256, 0, stream>>>(dm, dh, ws, xbuf);
    lstm_kernel<<<NH * 2, 512, 0, stream>>>(xbuf, Wih, Whh, bih, bhh, Wlin, blin, out);
}